// Round 5
// baseline (96.563 us; speedup 1.0000x reference)
//
#include <hip/hip_runtime.h>
#include <limits>

// Per-channel int4-codebook quantize/dequantize, bit-exact vs the jnp reference.
//
// Exact structure assumed (verified): grid sorted, grid[8-i] == -grid[8+i]
// (fp negation exact), grid[8] == 0, grid[15] == max. All codebook values are
// LOADED from the input grid.
//
// Magnitude domain: m = |xs| = fl(|x|*scale)  (|fl(y)| == fl(|y|) exactly),
// tab[k] = |grid value|, k = 0..8 (positive side caps at 7).
// Reference decision (searchsorted-left + |xs-vlo| <= |xs-vhi| -> vlo):
//   |fl(xs - v)| == fl(m - |v|) or fl(|v| - m) exactly by antisymmetry of fp
//   subtraction. Between tab[j] and tab[j+1] the predicate
//       pos: fl(t1 - m) <  fl(m - t0)   (tie -> lower value = lower mag)
//       neg: fl(t1 - m) <= fl(m - t0)   (tie -> lower value = higher mag)
//   is weakly monotone in m (each side is monotone, rounding preserves it),
//   so it has ONE exact fp32 flip point TH. We find TH by bit-bisection over
//   the fp32 lattice at setup (row-independent, 15 boundaries, 31 iters).
//   Per element: k = #{j : m >= TH[j]}, resolved as a +/-1 fixup around the
//   guess ki = rint(m * fl(1/step)) (guess error ~1e-6 index << 0.5, so the
//   true k is always within +/-1 of ki; sentinels -1/+INF absorb the edges).
// Dequant: dq[k] = fl(tab[k]/scale) (IEEE div); fl(-q/s) = -fl(q/s) exactly,
// so out = copysign(dq[k], x).

typedef float f32x4 __attribute__((ext_vector_type(4)));

constexpr int TPB = 256;
constexpr int VPT = 8;   // float4 per thread -> 8192 elements per block

__global__ __launch_bounds__(TPB) void quant_kernel(
    const f32x4* __restrict__ x,
    const float* __restrict__ alpha,
    const float* __restrict__ grid,
    f32x4*       __restrict__ out,
    int rowShift)            // log2(blocks per row)
{
    // Ball layout: pos base 0:  [0]=-1 sentinel, [1..7]=TH[0..6], [8]=[9]=INF
    //              neg base 10: [10]=-1,         [11..18]=TH[0..7], [19]=INF
    __shared__ float Ball[20];
    __shared__ float dq[9];

    const int tid = threadIdx.x;
    const int bid = blockIdx.x;
    const int row = bid >> rowShift;

    const float g15 = grid[15];              // max grid value
    const float a = alpha[row];
    const float scale = g15 / a;             // IEEE fp32 div, matches reference
    const float inv_step = 1.0f / grid[9];   // guess only
    const float INF = std::numeric_limits<float>::infinity();

    if (tid < 32) {
        const bool isPos = (tid < 7);
        const bool isNeg = (tid >= 8 && tid < 16);
        if (isPos || isNeg) {
            const int j = isPos ? tid : tid - 8;
            // tab(k) = k < 8 ? grid[8+k] : -grid[0]  (exact negation)
            const float t0 = grid[8 + j];                       // j <= 7
            const float t1 = (j + 1 < 8) ? grid[9 + j] : -grid[0];
            unsigned lob = __float_as_uint(t0);   // pred(t0) == false
            unsigned hib = __float_as_uint(t1);   // pred(t1) == true
            #pragma unroll 1
            for (int it = 0; it < 31; ++it) {
                if (hib - lob > 1u) {
                    unsigned mid = (lob + hib) >> 1;
                    float mm = __uint_as_float(mid);
                    float d1 = t1 - mm;           // exact reference ops
                    float d0 = mm - t0;
                    bool pred = isPos ? (d1 < d0) : (d1 <= d0);
                    if (pred) hib = mid; else lob = mid;
                }
            }
            Ball[(isPos ? 1 : 11) + j] = __uint_as_float(hib);
        } else if (tid >= 16 && tid < 25) {
            const int k = tid - 16;
            const float t = (k < 8) ? grid[8 + k] : -grid[0];
            dq[k] = t / scale;                    // IEEE div, matches reference
        } else if (tid == 25) { Ball[0]  = -1.0f;
        } else if (tid == 26) { Ball[8]  = INF;
        } else if (tid == 27) { Ball[9]  = INF;
        } else if (tid == 28) { Ball[10] = -1.0f;
        } else if (tid == 29) { Ball[19] = INF; }
    }
    __syncthreads();

    const long base = (long)bid * (TPB * VPT) + tid;      // float4 index

    f32x4 v[VPT];
    #pragma unroll
    for (int i = 0; i < VPT; ++i)
        v[i] = __builtin_nontemporal_load(&x[base + (long)i * TPB]);

    #pragma unroll
    for (int i = 0; i < VPT; ++i) {
        float res[4];
        #pragma unroll
        for (int e = 0; e < 4; ++e) {
            const float xv = v[i][e];
            const float m  = fabsf(xv) * scale;   // == |fl(x*scale)| exactly
            int ki = (int)rintf(m * inv_step);    // m >= 0 so ki >= 0
            ki = min(ki, 8);                      // pos overshoot fixed by INF/sentinel
            const int bb = (xv < 0.0f) ? 10 : 0;
            const float lo = Ball[bb + ki];       // TH[ki-1] (or -1 sentinel)
            const float hi = Ball[bb + ki + 1];   // TH[ki]   (or INF)
            ki += (m >= hi) ? 1 : 0;
            ki -= (m < lo) ? 1 : 0;
            const float q = dq[ki];               // 9 words -> broadcast-friendly
            res[e] = __builtin_copysignf(q, xv);
        }
        f32x4 o; o[0] = res[0]; o[1] = res[1]; o[2] = res[2]; o[3] = res[3];
        __builtin_nontemporal_store(o, &out[base + (long)i * TPB]);
    }
}

extern "C" void kernel_launch(void* const* d_in, const int* in_sizes, int n_in,
                              void* d_out, int out_size, void* d_ws, size_t ws_size,
                              hipStream_t stream) {
    const float* x     = (const float*)d_in[0];   // [C, F] fp32
    const float* alpha = (const float*)d_in[1];   // [C, 1] fp32
    const float* grid  = (const float*)d_in[2];   // [16] fp32, sorted
    float* out = (float*)d_out;

    int total = in_sizes[0];          // C*F = 67,108,864
    int C     = in_sizes[1];          // 4096
    int F     = total / C;            // 16384
    int vec4PerRow   = F / 4;         // 4096
    int vec4PerBlock = TPB * VPT;     // 2048
    int blocksPerRow = vec4PerRow / vec4PerBlock;   // 2
    int rowShift = 0;
    while ((1 << rowShift) < blocksPerRow) ++rowShift;  // = 1

    int blocks = C * blocksPerRow;    // 8192
    quant_kernel<<<blocks, TPB, 0, stream>>>(
        (const f32x4*)x, alpha, grid, (f32x4*)out, rowShift);
}